// Round 4
// baseline (625.067 us; speedup 1.0000x reference)
//
#include <hip/hip_runtime.h>
#include <hip/hip_bf16.h>

#define C 32
#define LN_EPS 1e-5f
#define P 8            // threads per superpoint in reduce kernels
#define SCAN_BLK 1024

__device__ __forceinline__ unsigned pack_bf16x2(float a, float b) {
    __hip_bfloat162 bb = __float22bfloat162_rn(make_float2(a, b));
    return *reinterpret_cast<unsigned*>(&bb);
}

// ---------- kVk1: fused [voxel fp32->bf16 convert] + [hist+rank atomics] -----
// thread t: if t < n_pts do the atomic; if t < n_chunk convert 16 floats.
__global__ __launch_bounds__(256) void kVk1(
    const int* __restrict__ sp_ids, int* __restrict__ count, int* __restrict__ rank,
    const float* __restrict__ vf, unsigned* __restrict__ vf16,
    int n_pts, int n_chunk)
{
    int t = blockIdx.x * 256 + threadIdx.x;
    if (t < n_pts) {
        int sp = sp_ids[t];
        rank[t] = atomicAdd(&count[sp], 1);
    }
    if (t < n_chunk) {
        const float4* src = (const float4*)vf + (size_t)t * 4;
        float4 a = src[0], b = src[1], c = src[2], d = src[3];
        uint4 o0, o1;
        o0.x = pack_bf16x2(a.x, a.y); o0.y = pack_bf16x2(a.z, a.w);
        o0.z = pack_bf16x2(b.x, b.y); o0.w = pack_bf16x2(b.z, b.w);
        o1.x = pack_bf16x2(c.x, c.y); o1.y = pack_bf16x2(c.z, c.w);
        o1.z = pack_bf16x2(d.x, d.y); o1.w = pack_bf16x2(d.z, d.w);
        uint4* dst = (uint4*)vf16 + (size_t)t * 2;
        dst[0] = o0; dst[1] = o1;
    }
}

// ---------- K1 (non-fused, for fallback tiers) -------------------------------
__global__ __launch_bounds__(256) void k1_hist_rank(
    const int* __restrict__ sp_ids, int* __restrict__ count,
    int* __restrict__ rank, int n)
{
    int p = blockIdx.x * 256 + threadIdx.x;
    if (p >= n) return;
    int sp = sp_ids[p];
    rank[p] = atomicAdd(&count[sp], 1);
}

// ---------- K2a/b/c: exclusive scan of counts --------------------------------
__global__ __launch_bounds__(SCAN_BLK) void k2a_scan_block(
    const int* __restrict__ count, int* __restrict__ off,
    int* __restrict__ bsum, int S)
{
    __shared__ int lds[SCAN_BLK];
    int t = threadIdx.x;
    int i = blockIdx.x * SCAN_BLK + t;
    int v = (i < S) ? count[i] : 0;
    lds[t] = v;
    __syncthreads();
    for (int d = 1; d < SCAN_BLK; d <<= 1) {
        int add = (t >= d) ? lds[t - d] : 0;
        __syncthreads();
        lds[t] += add;
        __syncthreads();
    }
    int incl = lds[t];
    if (i < S) off[i] = incl - v;
    if (t == SCAN_BLK - 1) bsum[blockIdx.x] = incl;
}

__global__ __launch_bounds__(64) void k2b_scan_bsums(int* __restrict__ bsum, int nb)
{
    int lane = threadIdx.x;
    int v = (lane < nb) ? bsum[lane] : 0;
    int own = v;
    for (int d = 1; d < 64; d <<= 1) {
        int u = __shfl_up(v, d, 64);
        if (lane >= d) v += u;
    }
    if (lane < nb) bsum[lane] = v - own;
}

__global__ __launch_bounds__(256) void k2c_add_prefix(
    int* __restrict__ off, const int* __restrict__ bsum, int S)
{
    int i = blockIdx.x * 256 + threadIdx.x;
    if (i >= S) return;
    off[i] += bsum[i / SCAN_BLK];
}

// ---------- kA: MLP + gather, writes one 128-B aligned record per point ------
// record j (8 uint4): [0..3] y bf16x32, [4].xyz = xyz fp32, rest zero pad.
template<bool BF16VF>
__global__ __launch_bounds__(256) void kA_rec(
    const void* __restrict__ vfeats,
    const float* __restrict__ xyz,
    const float* __restrict__ W1, const float* __restrict__ b1,
    const float* __restrict__ gamma, const float* __restrict__ beta,
    const float* __restrict__ W2, const float* __restrict__ b2,
    const int* __restrict__ p2v, const int* __restrict__ sp_ids,
    const int* __restrict__ rank, const int* __restrict__ off,
    uint4* __restrict__ recs, int n, int half)
{
    int t0 = blockIdx.x * 256 + threadIdx.x;
    #pragma unroll
    for (int u = 0; u < 2; ++u) {
        int p = t0 + u * half;
        if (p >= n) continue;

        float x0 = xyz[3 * p + 0];
        float x1 = xyz[3 * p + 1];
        float x2 = xyz[3 * p + 2];
        int v  = p2v[p];
        int sp = sp_ids[p];
        int j  = off[sp] + rank[p];

        // Linear(3,32)
        float h[C];
        #pragma unroll
        for (int c = 0; c < C; ++c)
            h[c] = fmaf(x0, W1[c], fmaf(x1, W1[C + c], fmaf(x2, W1[2 * C + c], b1[c])));

        // LayerNorm(32)
        float s = 0.f, s2 = 0.f;
        #pragma unroll
        for (int c = 0; c < C; ++c) { s += h[c]; s2 += h[c] * h[c]; }
        float mu   = s * (1.0f / C);
        float var  = fmaf(-mu, mu, s2 * (1.0f / C));
        float rstd = rsqrtf(var + LN_EPS);
        #pragma unroll
        for (int c = 0; c < C; ++c)
            h[c] = fmaxf(fmaf((h[c] - mu) * rstd, gamma[c], beta[c]), 0.0f);

        // acc = b2 + vf[v]
        float acc[C];
        if (BF16VF) {
            const uint4* g4 = (const uint4*)vfeats + (size_t)v * 4;
            uint4 g0 = g4[0], g1 = g4[1], g2 = g4[2], g3 = g4[3];
            unsigned gw[16] = { g0.x, g0.y, g0.z, g0.w, g1.x, g1.y, g1.z, g1.w,
                                g2.x, g2.y, g2.z, g2.w, g3.x, g3.y, g3.z, g3.w };
            #pragma unroll
            for (int q = 0; q < 16; ++q) {
                acc[2 * q + 0] = b2[2 * q + 0] + __uint_as_float(gw[q] << 16);
                acc[2 * q + 1] = b2[2 * q + 1] + __uint_as_float(gw[q] & 0xFFFF0000u);
            }
        } else {
            const float4* vf4 = (const float4*)((const float*)vfeats + (size_t)v * C);
            #pragma unroll
            for (int q = 0; q < 8; ++q) {
                float4 f = vf4[q];
                acc[4 * q + 0] = b2[4 * q + 0] + f.x;
                acc[4 * q + 1] = b2[4 * q + 1] + f.y;
                acc[4 * q + 2] = b2[4 * q + 2] + f.z;
                acc[4 * q + 3] = b2[4 * q + 3] + f.w;
            }
        }

        // acc += h @ W2
        #pragma unroll
        for (int k = 0; k < C; ++k) {
            float rk = h[k];
            #pragma unroll
            for (int c = 0; c < C; ++c)
                acc[c] = fmaf(rk, W2[k * C + c], acc[c]);
        }

        // pack + one full 128-B line store
        uint4* r = recs + (size_t)j * 8;
        uint4 y0, y1, y2, y3;
        y0.x = pack_bf16x2(acc[0],  acc[1]);  y0.y = pack_bf16x2(acc[2],  acc[3]);
        y0.z = pack_bf16x2(acc[4],  acc[5]);  y0.w = pack_bf16x2(acc[6],  acc[7]);
        y1.x = pack_bf16x2(acc[8],  acc[9]);  y1.y = pack_bf16x2(acc[10], acc[11]);
        y1.z = pack_bf16x2(acc[12], acc[13]); y1.w = pack_bf16x2(acc[14], acc[15]);
        y2.x = pack_bf16x2(acc[16], acc[17]); y2.y = pack_bf16x2(acc[18], acc[19]);
        y2.z = pack_bf16x2(acc[20], acc[21]); y2.w = pack_bf16x2(acc[22], acc[23]);
        y3.x = pack_bf16x2(acc[24], acc[25]); y3.y = pack_bf16x2(acc[26], acc[27]);
        y3.z = pack_bf16x2(acc[28], acc[29]); y3.w = pack_bf16x2(acc[30], acc[31]);
        r[0] = y0; r[1] = y1; r[2] = y2; r[3] = y3;
        r[4] = make_uint4(__float_as_uint(x0), __float_as_uint(x1), __float_as_uint(x2), 0u);
        uint4 z = make_uint4(0u, 0u, 0u, 0u);
        r[5] = z; r[6] = z; r[7] = z;
    }
}

// ---------- kB: sequential segmented mean over 128-B records -----------------
__global__ __launch_bounds__(256) void kB_rec(
    const uint4* __restrict__ recs,
    const int* __restrict__ off, const int* __restrict__ count,
    float* __restrict__ out_x, float* __restrict__ out_xyz, int S)
{
    int gt  = blockIdx.x * 256 + threadIdx.x;
    int sp  = gt >> 3;
    int sub = gt & 7;
    if (sp >= S) return;

    int n    = count[sp];
    int base = off[sp];

    float acc[C];
    #pragma unroll
    for (int c = 0; c < C; ++c) acc[c] = 0.f;
    float ax = 0.f, ay = 0.f, az = 0.f;

    for (int i = sub; i < n; i += P) {
        const uint4* r = recs + (size_t)(base + i) * 8;
        uint4 a = r[0], b = r[1], c4 = r[2], d = r[3], e = r[4];
        unsigned w[16] = { a.x, a.y, a.z, a.w, b.x, b.y, b.z, b.w,
                           c4.x, c4.y, c4.z, c4.w, d.x, d.y, d.z, d.w };
        #pragma unroll
        for (int q = 0; q < 16; ++q) {
            acc[2 * q + 0] += __uint_as_float(w[q] << 16);
            acc[2 * q + 1] += __uint_as_float(w[q] & 0xFFFF0000u);
        }
        ax += __uint_as_float(e.x);
        ay += __uint_as_float(e.y);
        az += __uint_as_float(e.z);
    }

    #pragma unroll
    for (int c = 0; c < C; ++c) {
        acc[c] += __shfl_xor(acc[c], 1);
        acc[c] += __shfl_xor(acc[c], 2);
        acc[c] += __shfl_xor(acc[c], 4);
    }
    ax += __shfl_xor(ax, 1); ax += __shfl_xor(ax, 2); ax += __shfl_xor(ax, 4);
    ay += __shfl_xor(ay, 1); ay += __shfl_xor(ay, 2); ay += __shfl_xor(ay, 4);
    az += __shfl_xor(az, 1); az += __shfl_xor(az, 2); az += __shfl_xor(az, 4);

    if (sub == 0) {
        float inv = 1.0f / fmaxf((float)n, 1.0f);
        float4* o4 = (float4*)(out_x + (size_t)sp * C);
        #pragma unroll
        for (int q = 0; q < 8; ++q) {
            float4 f;
            f.x = acc[4 * q + 0] * inv;
            f.y = acc[4 * q + 1] * inv;
            f.z = acc[4 * q + 2] * inv;
            f.w = acc[4 * q + 3] * inv;
            o4[q] = f;
        }
        out_xyz[3 * sp + 0] = ax * inv;
        out_xyz[3 * sp + 1] = ay * inv;
        out_xyz[3 * sp + 2] = az * inv;
    }
}

// ================= Tier-3 fallback: exact R3 structure =======================
__global__ __launch_bounds__(256) void kA_mlp_scatter(
    const float* __restrict__ voxel_feats, const float* __restrict__ xyz,
    const float* __restrict__ W1, const float* __restrict__ b1,
    const float* __restrict__ gamma, const float* __restrict__ beta,
    const float* __restrict__ W2, const float* __restrict__ b2,
    const int* __restrict__ p2v, const int* __restrict__ sp_ids,
    const int* __restrict__ rank, const int* __restrict__ off,
    unsigned int* __restrict__ y_s, float* __restrict__ xyz_s, int n)
{
    int p = blockIdx.x * 256 + threadIdx.x;
    if (p >= n) return;
    float x0 = xyz[3 * p + 0], x1 = xyz[3 * p + 1], x2 = xyz[3 * p + 2];
    int v = p2v[p], sp = sp_ids[p];
    int j = off[sp] + rank[p];
    float h[C];
    #pragma unroll
    for (int c = 0; c < C; ++c)
        h[c] = fmaf(x0, W1[c], fmaf(x1, W1[C + c], fmaf(x2, W1[2 * C + c], b1[c])));
    float s = 0.f, s2 = 0.f;
    #pragma unroll
    for (int c = 0; c < C; ++c) { s += h[c]; s2 += h[c] * h[c]; }
    float mu = s * (1.0f / C);
    float var = fmaf(-mu, mu, s2 * (1.0f / C));
    float rstd = rsqrtf(var + LN_EPS);
    #pragma unroll
    for (int c = 0; c < C; ++c)
        h[c] = fmaxf(fmaf((h[c] - mu) * rstd, gamma[c], beta[c]), 0.0f);
    float acc[C];
    const float4* vf4 = (const float4*)(voxel_feats + (size_t)v * C);
    #pragma unroll
    for (int q = 0; q < 8; ++q) {
        float4 f = vf4[q];
        acc[4 * q + 0] = b2[4 * q + 0] + f.x;
        acc[4 * q + 1] = b2[4 * q + 1] + f.y;
        acc[4 * q + 2] = b2[4 * q + 2] + f.z;
        acc[4 * q + 3] = b2[4 * q + 3] + f.w;
    }
    #pragma unroll
    for (int k = 0; k < C; ++k) {
        float rk = h[k];
        #pragma unroll
        for (int c = 0; c < C; ++c)
            acc[c] = fmaf(rk, W2[k * C + c], acc[c]);
    }
    unsigned int w[16];
    #pragma unroll
    for (int q = 0; q < 16; ++q) w[q] = pack_bf16x2(acc[2 * q], acc[2 * q + 1]);
    uint4* dst = (uint4*)(y_s + (size_t)j * 16);
    dst[0] = make_uint4(w[0], w[1], w[2], w[3]);
    dst[1] = make_uint4(w[4], w[5], w[6], w[7]);
    dst[2] = make_uint4(w[8], w[9], w[10], w[11]);
    dst[3] = make_uint4(w[12], w[13], w[14], w[15]);
    float* xd = xyz_s + (size_t)j * 3;
    xd[0] = x0; xd[1] = x1; xd[2] = x2;
}

__global__ __launch_bounds__(256) void kB_reduce(
    const unsigned int* __restrict__ y_s, const float* __restrict__ xyz_s,
    const int* __restrict__ off, const int* __restrict__ count,
    float* __restrict__ out_x, float* __restrict__ out_xyz, int S)
{
    int gt = blockIdx.x * 256 + threadIdx.x;
    int sp = gt >> 3, sub = gt & 7;
    if (sp >= S) return;
    int n = count[sp], base = off[sp];
    float acc[C];
    #pragma unroll
    for (int c = 0; c < C; ++c) acc[c] = 0.f;
    float ax = 0.f, ay = 0.f, az = 0.f;
    for (int i = sub; i < n; i += P) {
        const uint4* r4 = (const uint4*)(y_s + (size_t)(base + i) * 16);
        unsigned int w[16];
        *(uint4*)(w + 0) = r4[0]; *(uint4*)(w + 4) = r4[1];
        *(uint4*)(w + 8) = r4[2]; *(uint4*)(w + 12) = r4[3];
        #pragma unroll
        for (int q = 0; q < 16; ++q) {
            acc[2 * q + 0] += __uint_as_float(w[q] << 16);
            acc[2 * q + 1] += __uint_as_float(w[q] & 0xFFFF0000u);
        }
        const float* xp = xyz_s + (size_t)(base + i) * 3;
        ax += xp[0]; ay += xp[1]; az += xp[2];
    }
    #pragma unroll
    for (int c = 0; c < C; ++c) {
        acc[c] += __shfl_xor(acc[c], 1);
        acc[c] += __shfl_xor(acc[c], 2);
        acc[c] += __shfl_xor(acc[c], 4);
    }
    ax += __shfl_xor(ax, 1); ax += __shfl_xor(ax, 2); ax += __shfl_xor(ax, 4);
    ay += __shfl_xor(ay, 1); ay += __shfl_xor(ay, 2); ay += __shfl_xor(ay, 4);
    az += __shfl_xor(az, 1); az += __shfl_xor(az, 2); az += __shfl_xor(az, 4);
    if (sub == 0) {
        float inv = 1.0f / fmaxf((float)n, 1.0f);
        float4* o4 = (float4*)(out_x + (size_t)sp * C);
        #pragma unroll
        for (int q = 0; q < 8; ++q) {
            float4 f;
            f.x = acc[4 * q + 0] * inv; f.y = acc[4 * q + 1] * inv;
            f.z = acc[4 * q + 2] * inv; f.w = acc[4 * q + 3] * inv;
            o4[q] = f;
        }
        out_xyz[3 * sp + 0] = ax * inv;
        out_xyz[3 * sp + 1] = ay * inv;
        out_xyz[3 * sp + 2] = az * inv;
    }
}

extern "C" void kernel_launch(void* const* d_in, const int* in_sizes, int n_in,
                              void* d_out, int out_size, void* d_ws, size_t ws_size,
                              hipStream_t stream)
{
    const float* voxel_feats = (const float*)d_in[0];
    const float* xyz         = (const float*)d_in[1];
    const float* W1          = (const float*)d_in[2];
    const float* b1          = (const float*)d_in[3];
    const float* gamma       = (const float*)d_in[4];
    const float* beta        = (const float*)d_in[5];
    const float* W2          = (const float*)d_in[6];
    const float* b2          = (const float*)d_in[7];
    const int*   p2v         = (const int*)d_in[8];
    const int*   sp_ids      = (const int*)d_in[9];

    const int n_pts = in_sizes[8];
    const int n_vox = in_sizes[0] / C;
    const int S     = out_size / 35;

    float* out_x   = (float*)d_out;
    float* out_xyz = out_x + (size_t)S * C;

    // head (ints): count[S] | off[S] | bsum[64] | rank[N]
    int* count = (int*)d_ws;
    int* off   = count + S;
    int* bsum  = off + S;
    int* rank  = bsum + 64;

    size_t head_b = ((size_t)2 * S + 64 + (size_t)n_pts) * sizeof(int);
    head_b = (head_b + 255) & ~(size_t)255;
    size_t rec_b  = (size_t)n_pts * 128;
    size_t vf16_b = (size_t)n_vox * 64;

    bool tier1 = ws_size >= head_b + rec_b + vf16_b;
    bool tier2 = !tier1 && ws_size >= head_b + rec_b;

    int blk = 256;
    int gpts = (n_pts + blk - 1) / blk;
    int nb = (S + SCAN_BLK - 1) / SCAN_BLK;
    int n_thr = S * P;

    hipMemsetAsync(count, 0, (size_t)S * sizeof(int), stream);

    if (tier1) {
        uint4* recs = (uint4*)((char*)d_ws + head_b);
        unsigned* vf16 = (unsigned*)((char*)d_ws + head_b + rec_b);
        int n_chunk = n_vox * 2;   // 16 floats per chunk
        int gfuse = (max(n_pts, n_chunk) + blk - 1) / blk;

        kVk1<<<gfuse, blk, 0, stream>>>(sp_ids, count, rank,
                                        voxel_feats, vf16, n_pts, n_chunk);
        k2a_scan_block<<<nb, SCAN_BLK, 0, stream>>>(count, off, bsum, S);
        k2b_scan_bsums<<<1, 64, 0, stream>>>(bsum, nb);
        k2c_add_prefix<<<(S + blk - 1) / blk, blk, 0, stream>>>(off, bsum, S);

        int half = (n_pts + 1) / 2;
        kA_rec<true><<<(half + blk - 1) / blk, blk, 0, stream>>>(
            vf16, xyz, W1, b1, gamma, beta, W2, b2,
            p2v, sp_ids, rank, off, recs, n_pts, half);
        kB_rec<<<(n_thr + blk - 1) / blk, blk, 0, stream>>>(
            recs, off, count, out_x, out_xyz, S);
    } else if (tier2) {
        uint4* recs = (uint4*)((char*)d_ws + head_b);
        k1_hist_rank<<<gpts, blk, 0, stream>>>(sp_ids, count, rank, n_pts);
        k2a_scan_block<<<nb, SCAN_BLK, 0, stream>>>(count, off, bsum, S);
        k2b_scan_bsums<<<1, 64, 0, stream>>>(bsum, nb);
        k2c_add_prefix<<<(S + blk - 1) / blk, blk, 0, stream>>>(off, bsum, S);

        int half = (n_pts + 1) / 2;
        kA_rec<false><<<(half + blk - 1) / blk, blk, 0, stream>>>(
            voxel_feats, xyz, W1, b1, gamma, beta, W2, b2,
            p2v, sp_ids, rank, off, recs, n_pts, half);
        kB_rec<<<(n_thr + blk - 1) / blk, blk, 0, stream>>>(
            recs, off, count, out_x, out_xyz, S);
    } else {
        // Tier-3: exact R3 path
        unsigned int* y_s = (unsigned int*)((char*)d_ws + head_b);
        float* xyz_s = (float*)((char*)d_ws + head_b + (size_t)n_pts * 64);
        k1_hist_rank<<<gpts, blk, 0, stream>>>(sp_ids, count, rank, n_pts);
        k2a_scan_block<<<nb, SCAN_BLK, 0, stream>>>(count, off, bsum, S);
        k2b_scan_bsums<<<1, 64, 0, stream>>>(bsum, nb);
        k2c_add_prefix<<<(S + blk - 1) / blk, blk, 0, stream>>>(off, bsum, S);
        kA_mlp_scatter<<<gpts, blk, 0, stream>>>(
            voxel_feats, xyz, W1, b1, gamma, beta, W2, b2,
            p2v, sp_ids, rank, off, y_s, xyz_s, n_pts);
        kB_reduce<<<(n_thr + blk - 1) / blk, blk, 0, stream>>>(
            y_s, xyz_s, off, count, out_x, out_xyz, S);
    }
}

// Round 5
// 526.858 us; speedup vs baseline: 1.1864x; 1.1864x over previous
//
#include <hip/hip_runtime.h>
#include <hip/hip_bf16.h>

#define C 32
#define LN_EPS 1e-5f
#define P 8            // threads per superpoint in reduce
#define SCAN_BLK 1024

__device__ __forceinline__ unsigned pack_bf16x2(float a, float b) {
    __hip_bfloat162 bb = __float22bfloat162_rn(make_float2(a, b));
    return *reinterpret_cast<unsigned*>(&bb);
}

// ---------- kA1: fused [hist+rank atomic] + MLP + SEQUENTIAL y write ---------
__global__ __launch_bounds__(256) void kA1_rank_mlp(
    const float* __restrict__ voxel_feats,
    const float* __restrict__ xyz,
    const float* __restrict__ W1, const float* __restrict__ b1,
    const float* __restrict__ gamma, const float* __restrict__ beta,
    const float* __restrict__ W2, const float* __restrict__ b2,
    const int* __restrict__ p2v, const int* __restrict__ sp_ids,
    int* __restrict__ count, int* __restrict__ rank,
    uint4* __restrict__ y_s,            // [N*4] : 64 B bf16 row per point
    int n)
{
    int p = blockIdx.x * 256 + threadIdx.x;
    if (p >= n) return;

    // independent work first: atomic rank (latency hides under MLP below)
    int sp = sp_ids[p];
    rank[p] = atomicAdd(&count[sp], 1);

    // issue voxel gather early; result consumed only at the very end
    int v = p2v[p];
    const float4* vrow = (const float4*)(voxel_feats + (size_t)v * C);
    float4 g0 = vrow[0], g1 = vrow[1], g2 = vrow[2], g3 = vrow[3];
    float4 g4 = vrow[4], g5 = vrow[5], g6 = vrow[6], g7 = vrow[7];

    float x0 = xyz[3 * p + 0];
    float x1 = xyz[3 * p + 1];
    float x2 = xyz[3 * p + 2];

    // Linear(3,32)
    float h[C];
    #pragma unroll
    for (int c = 0; c < C; ++c)
        h[c] = fmaf(x0, W1[c], fmaf(x1, W1[C + c], fmaf(x2, W1[2 * C + c], b1[c])));

    // LayerNorm(32)
    float s = 0.f, s2 = 0.f;
    #pragma unroll
    for (int c = 0; c < C; ++c) { s += h[c]; s2 += h[c] * h[c]; }
    float mu   = s * (1.0f / C);
    float var  = fmaf(-mu, mu, s2 * (1.0f / C));
    float rstd = rsqrtf(var + LN_EPS);
    #pragma unroll
    for (int c = 0; c < C; ++c)
        h[c] = fmaxf(fmaf((h[c] - mu) * rstd, gamma[c], beta[c]), 0.0f);

    // acc = b2 + h @ W2   (vf added afterwards so its loads have max slack)
    float acc[C];
    #pragma unroll
    for (int c = 0; c < C; ++c) acc[c] = b2[c];
    #pragma unroll
    for (int k = 0; k < C; ++k) {
        float rk = h[k];
        #pragma unroll
        for (int c = 0; c < C; ++c)
            acc[c] = fmaf(rk, W2[k * C + c], acc[c]);
    }

    // add gathered voxel row
    float gf[C] = { g0.x,g0.y,g0.z,g0.w, g1.x,g1.y,g1.z,g1.w,
                    g2.x,g2.y,g2.z,g2.w, g3.x,g3.y,g3.z,g3.w,
                    g4.x,g4.y,g4.z,g4.w, g5.x,g5.y,g5.z,g5.w,
                    g6.x,g6.y,g6.z,g6.w, g7.x,g7.y,g7.z,g7.w };
    #pragma unroll
    for (int c = 0; c < C; ++c) acc[c] += gf[c];

    // pack bf16 and store 64 B at sequential position p (perfectly coalesced)
    uint4 y0, y1, y2, y3;
    y0.x = pack_bf16x2(acc[0],  acc[1]);  y0.y = pack_bf16x2(acc[2],  acc[3]);
    y0.z = pack_bf16x2(acc[4],  acc[5]);  y0.w = pack_bf16x2(acc[6],  acc[7]);
    y1.x = pack_bf16x2(acc[8],  acc[9]);  y1.y = pack_bf16x2(acc[10], acc[11]);
    y1.z = pack_bf16x2(acc[12], acc[13]); y1.w = pack_bf16x2(acc[14], acc[15]);
    y2.x = pack_bf16x2(acc[16], acc[17]); y2.y = pack_bf16x2(acc[18], acc[19]);
    y2.z = pack_bf16x2(acc[20], acc[21]); y2.w = pack_bf16x2(acc[22], acc[23]);
    y3.x = pack_bf16x2(acc[24], acc[25]); y3.y = pack_bf16x2(acc[26], acc[27]);
    y3.z = pack_bf16x2(acc[28], acc[29]); y3.w = pack_bf16x2(acc[30], acc[31]);
    uint4* dst = y_s + (size_t)p * 4;
    dst[0] = y0; dst[1] = y1; dst[2] = y2; dst[3] = y3;
}

// ---------- K2a/b/c: exclusive scan of counts --------------------------------
__global__ __launch_bounds__(SCAN_BLK) void k2a_scan_block(
    const int* __restrict__ count, int* __restrict__ off,
    int* __restrict__ bsum, int S)
{
    __shared__ int lds[SCAN_BLK];
    int t = threadIdx.x;
    int i = blockIdx.x * SCAN_BLK + t;
    int v = (i < S) ? count[i] : 0;
    lds[t] = v;
    __syncthreads();
    for (int d = 1; d < SCAN_BLK; d <<= 1) {
        int add = (t >= d) ? lds[t - d] : 0;
        __syncthreads();
        lds[t] += add;
        __syncthreads();
    }
    int incl = lds[t];
    if (i < S) off[i] = incl - v;
    if (t == SCAN_BLK - 1) bsum[blockIdx.x] = incl;
}

__global__ __launch_bounds__(64) void k2b_scan_bsums(int* __restrict__ bsum, int nb)
{
    int lane = threadIdx.x;
    int v = (lane < nb) ? bsum[lane] : 0;
    int own = v;
    for (int d = 1; d < 64; d <<= 1) {
        int u = __shfl_up(v, d, 64);
        if (lane >= d) v += u;
    }
    if (lane < nb) bsum[lane] = v - own;
}

__global__ __launch_bounds__(256) void k2c_add_prefix(
    int* __restrict__ off, const int* __restrict__ bsum, int S)
{
    int i = blockIdx.x * 256 + threadIdx.x;
    if (i >= S) return;
    off[i] += bsum[i / SCAN_BLK];
}

// ---------- k3: build inverse permutation (4-B scatter into 8 MB, L2-friendly)
__global__ __launch_bounds__(256) void k3_reorder(
    const int* __restrict__ sp_ids, const int* __restrict__ rank,
    const int* __restrict__ off, int* __restrict__ order, int n)
{
    int p = blockIdx.x * 256 + threadIdx.x;
    if (p >= n) return;
    int sp = sp_ids[p];
    order[off[sp] + rank[p]] = p;
}

// ---------- kB: segmented mean; streams order, random-gathers y + xyz --------
__global__ __launch_bounds__(256) void kB_gather_reduce(
    const uint4* __restrict__ y_s,          // [N*4]
    const float* __restrict__ xyz,          // original input [N,3]
    const int* __restrict__ order,
    const int* __restrict__ off, const int* __restrict__ count,
    float* __restrict__ out_x, float* __restrict__ out_xyz, int S)
{
    int gt  = blockIdx.x * 256 + threadIdx.x;
    int sp  = gt >> 3;
    int sub = gt & 7;
    if (sp >= S) return;

    int n    = count[sp];
    int base = off[sp];

    float acc[C];
    #pragma unroll
    for (int c = 0; c < C; ++c) acc[c] = 0.f;
    float ax = 0.f, ay = 0.f, az = 0.f;

    for (int i = sub; i < n; i += P) {
        int o = order[base + i];
        const uint4* r = y_s + (size_t)o * 4;
        uint4 a = r[0], b = r[1], c4 = r[2], d = r[3];
        const float* xp = xyz + 3 * (size_t)o;
        float px = xp[0], py = xp[1], pz = xp[2];
        unsigned w[16] = { a.x, a.y, a.z, a.w, b.x, b.y, b.z, b.w,
                           c4.x, c4.y, c4.z, c4.w, d.x, d.y, d.z, d.w };
        #pragma unroll
        for (int q = 0; q < 16; ++q) {
            acc[2 * q + 0] += __uint_as_float(w[q] << 16);
            acc[2 * q + 1] += __uint_as_float(w[q] & 0xFFFF0000u);
        }
        ax += px; ay += py; az += pz;
    }

    #pragma unroll
    for (int c = 0; c < C; ++c) {
        acc[c] += __shfl_xor(acc[c], 1);
        acc[c] += __shfl_xor(acc[c], 2);
        acc[c] += __shfl_xor(acc[c], 4);
    }
    ax += __shfl_xor(ax, 1); ax += __shfl_xor(ax, 2); ax += __shfl_xor(ax, 4);
    ay += __shfl_xor(ay, 1); ay += __shfl_xor(ay, 2); ay += __shfl_xor(ay, 4);
    az += __shfl_xor(az, 1); az += __shfl_xor(az, 2); az += __shfl_xor(az, 4);

    if (sub == 0) {
        float inv = 1.0f / fmaxf((float)n, 1.0f);
        float4* o4 = (float4*)(out_x + (size_t)sp * C);
        #pragma unroll
        for (int q = 0; q < 8; ++q) {
            float4 f;
            f.x = acc[4 * q + 0] * inv;
            f.y = acc[4 * q + 1] * inv;
            f.z = acc[4 * q + 2] * inv;
            f.w = acc[4 * q + 3] * inv;
            o4[q] = f;
        }
        out_xyz[3 * sp + 0] = ax * inv;
        out_xyz[3 * sp + 1] = ay * inv;
        out_xyz[3 * sp + 2] = az * inv;
    }
}

// ---------- fallback (tiny ws): R2-style recompute-in-reduce -----------------
__global__ __launch_bounds__(256) void k1_hist_rank(
    const int* __restrict__ sp_ids, int* __restrict__ count,
    int* __restrict__ rank, int n)
{
    int p = blockIdx.x * 256 + threadIdx.x;
    if (p >= n) return;
    rank[p] = atomicAdd(&count[sp_ids[p]], 1);
}

__global__ __launch_bounds__(256) void k4_segment_mlp_mean(
    const float* __restrict__ voxel_feats, const float* __restrict__ xyz,
    const float* __restrict__ W1, const float* __restrict__ b1,
    const float* __restrict__ gamma, const float* __restrict__ beta,
    const float* __restrict__ W2, const float* __restrict__ b2,
    const int* __restrict__ p2v, const int* __restrict__ order,
    const int* __restrict__ off, const int* __restrict__ count,
    float* __restrict__ out_x, float* __restrict__ out_xyz, int S)
{
    int gt = blockIdx.x * 256 + threadIdx.x;
    int sp = gt >> 3, sub = gt & 7;
    if (sp >= S) return;
    int n = count[sp], base = off[sp];
    float acc[C];
    #pragma unroll
    for (int c = 0; c < C; ++c) acc[c] = 0.f;
    float ax = 0.f, ay = 0.f, az = 0.f;
    int my_pts = 0;
    for (int i = sub; i < n; i += P) {
        int p = order[base + i];
        float x0 = xyz[3 * p + 0], x1 = xyz[3 * p + 1], x2 = xyz[3 * p + 2];
        int v = p2v[p];
        float h[C];
        #pragma unroll
        for (int c = 0; c < C; ++c)
            h[c] = fmaf(x0, W1[c], fmaf(x1, W1[C + c], fmaf(x2, W1[2 * C + c], b1[c])));
        float s = 0.f, s2 = 0.f;
        #pragma unroll
        for (int c = 0; c < C; ++c) { s += h[c]; s2 += h[c] * h[c]; }
        float mu = s * (1.0f / C);
        float var = fmaf(-mu, mu, s2 * (1.0f / C));
        float rstd = rsqrtf(var + LN_EPS);
        #pragma unroll
        for (int c = 0; c < C; ++c)
            h[c] = fmaxf(fmaf((h[c] - mu) * rstd, gamma[c], beta[c]), 0.0f);
        const float4* vf4 = (const float4*)(voxel_feats + (size_t)v * C);
        #pragma unroll
        for (int q = 0; q < 8; ++q) {
            float4 f = vf4[q];
            acc[4 * q + 0] += f.x; acc[4 * q + 1] += f.y;
            acc[4 * q + 2] += f.z; acc[4 * q + 3] += f.w;
        }
        #pragma unroll
        for (int k = 0; k < C; ++k) {
            float rk = h[k];
            #pragma unroll
            for (int c = 0; c < C; ++c)
                acc[c] = fmaf(rk, W2[k * C + c], acc[c]);
        }
        ax += x0; ay += x1; az += x2;
        ++my_pts;
    }
    float fpts = (float)my_pts;
    #pragma unroll
    for (int c = 0; c < C; ++c) acc[c] = fmaf(fpts, b2[c], acc[c]);
    #pragma unroll
    for (int c = 0; c < C; ++c) {
        acc[c] += __shfl_xor(acc[c], 1);
        acc[c] += __shfl_xor(acc[c], 2);
        acc[c] += __shfl_xor(acc[c], 4);
    }
    ax += __shfl_xor(ax, 1); ax += __shfl_xor(ax, 2); ax += __shfl_xor(ax, 4);
    ay += __shfl_xor(ay, 1); ay += __shfl_xor(ay, 2); ay += __shfl_xor(ay, 4);
    az += __shfl_xor(az, 1); az += __shfl_xor(az, 2); az += __shfl_xor(az, 4);
    if (sub == 0) {
        float inv = 1.0f / fmaxf((float)n, 1.0f);
        float4* o4 = (float4*)(out_x + (size_t)sp * C);
        #pragma unroll
        for (int q = 0; q < 8; ++q) {
            float4 f;
            f.x = acc[4 * q + 0] * inv; f.y = acc[4 * q + 1] * inv;
            f.z = acc[4 * q + 2] * inv; f.w = acc[4 * q + 3] * inv;
            o4[q] = f;
        }
        out_xyz[3 * sp + 0] = ax * inv;
        out_xyz[3 * sp + 1] = ay * inv;
        out_xyz[3 * sp + 2] = az * inv;
    }
}

extern "C" void kernel_launch(void* const* d_in, const int* in_sizes, int n_in,
                              void* d_out, int out_size, void* d_ws, size_t ws_size,
                              hipStream_t stream)
{
    const float* voxel_feats = (const float*)d_in[0];
    const float* xyz         = (const float*)d_in[1];
    const float* W1          = (const float*)d_in[2];
    const float* b1          = (const float*)d_in[3];
    const float* gamma       = (const float*)d_in[4];
    const float* beta        = (const float*)d_in[5];
    const float* W2          = (const float*)d_in[6];
    const float* b2          = (const float*)d_in[7];
    const int*   p2v         = (const int*)d_in[8];
    const int*   sp_ids      = (const int*)d_in[9];

    const int n_pts = in_sizes[8];
    const int S     = out_size / 35;

    float* out_x   = (float*)d_out;
    float* out_xyz = out_x + (size_t)S * C;

    // ws layout (ints): count[S] | off[S] | bsum[64] | rank[N] | order[N] | ...y_s
    int* count = (int*)d_ws;
    int* off   = count + S;
    int* bsum  = off + S;
    int* rank  = bsum + 64;
    int* order = rank + n_pts;

    size_t head_b = ((size_t)2 * S + 64 + (size_t)2 * n_pts) * sizeof(int);
    head_b = (head_b + 255) & ~(size_t)255;
    size_t y_b = (size_t)n_pts * 64;

    int blk = 256;
    int gpts = (n_pts + blk - 1) / blk;
    int nb = (S + SCAN_BLK - 1) / SCAN_BLK;
    int n_thr = S * P;

    hipMemsetAsync(count, 0, (size_t)S * sizeof(int), stream);

    if (ws_size >= head_b + y_b) {
        uint4* y_s = (uint4*)((char*)d_ws + head_b);

        kA1_rank_mlp<<<gpts, blk, 0, stream>>>(
            voxel_feats, xyz, W1, b1, gamma, beta, W2, b2,
            p2v, sp_ids, count, rank, y_s, n_pts);
        k2a_scan_block<<<nb, SCAN_BLK, 0, stream>>>(count, off, bsum, S);
        k2b_scan_bsums<<<1, 64, 0, stream>>>(bsum, nb);
        k2c_add_prefix<<<(S + blk - 1) / blk, blk, 0, stream>>>(off, bsum, S);
        k3_reorder<<<gpts, blk, 0, stream>>>(sp_ids, rank, off, order, n_pts);
        kB_gather_reduce<<<(n_thr + blk - 1) / blk, blk, 0, stream>>>(
            y_s, xyz, order, off, count, out_x, out_xyz, S);
    } else {
        k1_hist_rank<<<gpts, blk, 0, stream>>>(sp_ids, count, rank, n_pts);
        k2a_scan_block<<<nb, SCAN_BLK, 0, stream>>>(count, off, bsum, S);
        k2b_scan_bsums<<<1, 64, 0, stream>>>(bsum, nb);
        k2c_add_prefix<<<(S + blk - 1) / blk, blk, 0, stream>>>(off, bsum, S);
        k3_reorder<<<gpts, blk, 0, stream>>>(sp_ids, rank, off, order, n_pts);
        k4_segment_mlp_mean<<<(n_thr + blk - 1) / blk, blk, 0, stream>>>(
            voxel_feats, xyz, W1, b1, gamma, beta, W2, b2,
            p2v, order, off, count, out_x, out_xyz, S);
    }
}

// Round 6
// 518.414 us; speedup vs baseline: 1.2057x; 1.0163x over previous
//
#include <hip/hip_runtime.h>
#include <hip/hip_bf16.h>

#define C 32
#define LN_EPS 1e-5f
#define P 8            // threads per superpoint in reduce
#define SCAN_BLK 1024

__device__ __forceinline__ unsigned pack_bf16x2(float a, float b) {
    __hip_bfloat162 bb = __float22bfloat162_rn(make_float2(a, b));
    return *reinterpret_cast<unsigned*>(&bb);
}

// ---------- kA1: fused [hist+rank atomic] + MLP + SEQUENTIAL y write ---------
__global__ __launch_bounds__(256) void kA1_rank_mlp(
    const float* __restrict__ voxel_feats,
    const float* __restrict__ xyz,
    const float* __restrict__ W1, const float* __restrict__ b1,
    const float* __restrict__ gamma, const float* __restrict__ beta,
    const float* __restrict__ W2, const float* __restrict__ b2,
    const int* __restrict__ p2v, const int* __restrict__ sp_ids,
    int* __restrict__ count, int* __restrict__ rank,
    uint4* __restrict__ y_s,            // [N*4] : 64 B bf16 row per point
    int n)
{
    int p = blockIdx.x * 256 + threadIdx.x;
    if (p >= n) return;

    // independent work first: atomic rank (latency hides under MLP below)
    int sp = sp_ids[p];
    rank[p] = atomicAdd(&count[sp], 1);

    // issue voxel gather early; result consumed only at the very end
    int v = p2v[p];
    const float4* vrow = (const float4*)(voxel_feats + (size_t)v * C);
    float4 g0 = vrow[0], g1 = vrow[1], g2 = vrow[2], g3 = vrow[3];
    float4 g4 = vrow[4], g5 = vrow[5], g6 = vrow[6], g7 = vrow[7];

    float x0 = xyz[3 * p + 0];
    float x1 = xyz[3 * p + 1];
    float x2 = xyz[3 * p + 2];

    // Linear(3,32)
    float h[C];
    #pragma unroll
    for (int c = 0; c < C; ++c)
        h[c] = fmaf(x0, W1[c], fmaf(x1, W1[C + c], fmaf(x2, W1[2 * C + c], b1[c])));

    // LayerNorm(32)
    float s = 0.f, s2 = 0.f;
    #pragma unroll
    for (int c = 0; c < C; ++c) { s += h[c]; s2 += h[c] * h[c]; }
    float mu   = s * (1.0f / C);
    float var  = fmaf(-mu, mu, s2 * (1.0f / C));
    float rstd = rsqrtf(var + LN_EPS);
    #pragma unroll
    for (int c = 0; c < C; ++c)
        h[c] = fmaxf(fmaf((h[c] - mu) * rstd, gamma[c], beta[c]), 0.0f);

    // acc = b2 + h @ W2
    float acc[C];
    #pragma unroll
    for (int c = 0; c < C; ++c) acc[c] = b2[c];
    #pragma unroll
    for (int k = 0; k < C; ++k) {
        float rk = h[k];
        #pragma unroll
        for (int c = 0; c < C; ++c)
            acc[c] = fmaf(rk, W2[k * C + c], acc[c]);
    }

    // add gathered voxel row
    float gf[C] = { g0.x,g0.y,g0.z,g0.w, g1.x,g1.y,g1.z,g1.w,
                    g2.x,g2.y,g2.z,g2.w, g3.x,g3.y,g3.z,g3.w,
                    g4.x,g4.y,g4.z,g4.w, g5.x,g5.y,g5.z,g5.w,
                    g6.x,g6.y,g6.z,g6.w, g7.x,g7.y,g7.z,g7.w };
    #pragma unroll
    for (int c = 0; c < C; ++c) acc[c] += gf[c];

    // pack bf16 and store 64 B at sequential position p
    uint4 y0, y1, y2, y3;
    y0.x = pack_bf16x2(acc[0],  acc[1]);  y0.y = pack_bf16x2(acc[2],  acc[3]);
    y0.z = pack_bf16x2(acc[4],  acc[5]);  y0.w = pack_bf16x2(acc[6],  acc[7]);
    y1.x = pack_bf16x2(acc[8],  acc[9]);  y1.y = pack_bf16x2(acc[10], acc[11]);
    y1.z = pack_bf16x2(acc[12], acc[13]); y1.w = pack_bf16x2(acc[14], acc[15]);
    y2.x = pack_bf16x2(acc[16], acc[17]); y2.y = pack_bf16x2(acc[18], acc[19]);
    y2.z = pack_bf16x2(acc[20], acc[21]); y2.w = pack_bf16x2(acc[22], acc[23]);
    y3.x = pack_bf16x2(acc[24], acc[25]); y3.y = pack_bf16x2(acc[26], acc[27]);
    y3.z = pack_bf16x2(acc[28], acc[29]); y3.w = pack_bf16x2(acc[30], acc[31]);
    uint4* dst = y_s + (size_t)p * 4;
    dst[0] = y0; dst[1] = y1; dst[2] = y2; dst[3] = y3;
}

// ---------- K2a/b/c: exclusive scan of counts --------------------------------
__global__ __launch_bounds__(SCAN_BLK) void k2a_scan_block(
    const int* __restrict__ count, int* __restrict__ off,
    int* __restrict__ bsum, int S)
{
    __shared__ int lds[SCAN_BLK];
    int t = threadIdx.x;
    int i = blockIdx.x * SCAN_BLK + t;
    int v = (i < S) ? count[i] : 0;
    lds[t] = v;
    __syncthreads();
    for (int d = 1; d < SCAN_BLK; d <<= 1) {
        int add = (t >= d) ? lds[t - d] : 0;
        __syncthreads();
        lds[t] += add;
        __syncthreads();
    }
    int incl = lds[t];
    if (i < S) off[i] = incl - v;
    if (t == SCAN_BLK - 1) bsum[blockIdx.x] = incl;
}

__global__ __launch_bounds__(64) void k2b_scan_bsums(int* __restrict__ bsum, int nb)
{
    int lane = threadIdx.x;
    int v = (lane < nb) ? bsum[lane] : 0;
    int own = v;
    for (int d = 1; d < 64; d <<= 1) {
        int u = __shfl_up(v, d, 64);
        if (lane >= d) v += u;
    }
    if (lane < nb) bsum[lane] = v - own;
}

__global__ __launch_bounds__(256) void k2c_add_prefix(
    int* __restrict__ off, const int* __restrict__ bsum, int S)
{
    int i = blockIdx.x * 256 + threadIdx.x;
    if (i >= S) return;
    off[i] += bsum[i / SCAN_BLK];
}

// ---------- k3x: scatter 16-B {x,y,z,point_id} records into sp order ---------
__global__ __launch_bounds__(256) void k3x_scatter16(
    const int* __restrict__ sp_ids, const int* __restrict__ rank,
    const int* __restrict__ off, const float* __restrict__ xyz,
    uint4* __restrict__ xyzp, int n)
{
    int p = blockIdx.x * 256 + threadIdx.x;
    if (p >= n) return;
    int sp = sp_ids[p];
    int j  = off[sp] + rank[p];
    xyzp[j] = make_uint4(__float_as_uint(xyz[3 * p + 0]),
                         __float_as_uint(xyz[3 * p + 1]),
                         __float_as_uint(xyz[3 * p + 2]),
                         (unsigned)p);
}

// ---------- kB2: sequential xyzp stream + ONE random y read per point --------
__global__ __launch_bounds__(256) void kB2_reduce(
    const uint4* __restrict__ y_s,          // [N*4]
    const uint4* __restrict__ xyzp,         // [N] sp-ordered {x,y,z,p}
    const int* __restrict__ off, const int* __restrict__ count,
    float* __restrict__ out_x, float* __restrict__ out_xyz, int S)
{
    int gt  = blockIdx.x * 256 + threadIdx.x;
    int sp  = gt >> 3;
    int sub = gt & 7;
    if (sp >= S) return;

    int n    = count[sp];
    int base = off[sp];

    float acc[C];
    #pragma unroll
    for (int c = 0; c < C; ++c) acc[c] = 0.f;
    float ax = 0.f, ay = 0.f, az = 0.f;

    int i = sub;
    // 2-way unrolled: two records' y loads in flight simultaneously
    for (; i + P < n; i += 2 * P) {
        uint4 r0 = xyzp[base + i];
        uint4 r1 = xyzp[base + i + P];
        const uint4* q0 = y_s + (size_t)r0.w * 4;
        const uint4* q1 = y_s + (size_t)r1.w * 4;
        uint4 a0 = q0[0], b0 = q0[1], c0 = q0[2], d0 = q0[3];
        uint4 a1 = q1[0], b1_ = q1[1], c1 = q1[2], d1 = q1[3];
        ax += __uint_as_float(r0.x) + __uint_as_float(r1.x);
        ay += __uint_as_float(r0.y) + __uint_as_float(r1.y);
        az += __uint_as_float(r0.z) + __uint_as_float(r1.z);
        unsigned w0[16] = { a0.x,a0.y,a0.z,a0.w, b0.x,b0.y,b0.z,b0.w,
                            c0.x,c0.y,c0.z,c0.w, d0.x,d0.y,d0.z,d0.w };
        unsigned w1[16] = { a1.x,a1.y,a1.z,a1.w, b1_.x,b1_.y,b1_.z,b1_.w,
                            c1.x,c1.y,c1.z,c1.w, d1.x,d1.y,d1.z,d1.w };
        #pragma unroll
        for (int q = 0; q < 16; ++q) {
            acc[2 * q + 0] += __uint_as_float(w0[q] << 16) + __uint_as_float(w1[q] << 16);
            acc[2 * q + 1] += __uint_as_float(w0[q] & 0xFFFF0000u) + __uint_as_float(w1[q] & 0xFFFF0000u);
        }
    }
    if (i < n) {
        uint4 r0 = xyzp[base + i];
        const uint4* q0 = y_s + (size_t)r0.w * 4;
        uint4 a0 = q0[0], b0 = q0[1], c0 = q0[2], d0 = q0[3];
        ax += __uint_as_float(r0.x);
        ay += __uint_as_float(r0.y);
        az += __uint_as_float(r0.z);
        unsigned w0[16] = { a0.x,a0.y,a0.z,a0.w, b0.x,b0.y,b0.z,b0.w,
                            c0.x,c0.y,c0.z,c0.w, d0.x,d0.y,d0.z,d0.w };
        #pragma unroll
        for (int q = 0; q < 16; ++q) {
            acc[2 * q + 0] += __uint_as_float(w0[q] << 16);
            acc[2 * q + 1] += __uint_as_float(w0[q] & 0xFFFF0000u);
        }
    }

    #pragma unroll
    for (int c = 0; c < C; ++c) {
        acc[c] += __shfl_xor(acc[c], 1);
        acc[c] += __shfl_xor(acc[c], 2);
        acc[c] += __shfl_xor(acc[c], 4);
    }
    ax += __shfl_xor(ax, 1); ax += __shfl_xor(ax, 2); ax += __shfl_xor(ax, 4);
    ay += __shfl_xor(ay, 1); ay += __shfl_xor(ay, 2); ay += __shfl_xor(ay, 4);
    az += __shfl_xor(az, 1); az += __shfl_xor(az, 2); az += __shfl_xor(az, 4);

    if (sub == 0) {
        float inv = 1.0f / fmaxf((float)n, 1.0f);
        float4* o4 = (float4*)(out_x + (size_t)sp * C);
        #pragma unroll
        for (int q = 0; q < 8; ++q) {
            float4 f;
            f.x = acc[4 * q + 0] * inv;
            f.y = acc[4 * q + 1] * inv;
            f.z = acc[4 * q + 2] * inv;
            f.w = acc[4 * q + 3] * inv;
            o4[q] = f;
        }
        out_xyz[3 * sp + 0] = ax * inv;
        out_xyz[3 * sp + 1] = ay * inv;
        out_xyz[3 * sp + 2] = az * inv;
    }
}

// ---------- fallback tier (R5 path) ------------------------------------------
__global__ __launch_bounds__(256) void k3_reorder(
    const int* __restrict__ sp_ids, const int* __restrict__ rank,
    const int* __restrict__ off, int* __restrict__ order, int n)
{
    int p = blockIdx.x * 256 + threadIdx.x;
    if (p >= n) return;
    order[off[sp_ids[p]] + rank[p]] = p;
}

__global__ __launch_bounds__(256) void kB_gather_reduce(
    const uint4* __restrict__ y_s, const float* __restrict__ xyz,
    const int* __restrict__ order,
    const int* __restrict__ off, const int* __restrict__ count,
    float* __restrict__ out_x, float* __restrict__ out_xyz, int S)
{
    int gt = blockIdx.x * 256 + threadIdx.x;
    int sp = gt >> 3, sub = gt & 7;
    if (sp >= S) return;
    int n = count[sp], base = off[sp];
    float acc[C];
    #pragma unroll
    for (int c = 0; c < C; ++c) acc[c] = 0.f;
    float ax = 0.f, ay = 0.f, az = 0.f;
    for (int i = sub; i < n; i += P) {
        int o = order[base + i];
        const uint4* r = y_s + (size_t)o * 4;
        uint4 a = r[0], b = r[1], c4 = r[2], d = r[3];
        const float* xp = xyz + 3 * (size_t)o;
        ax += xp[0]; ay += xp[1]; az += xp[2];
        unsigned w[16] = { a.x,a.y,a.z,a.w, b.x,b.y,b.z,b.w,
                           c4.x,c4.y,c4.z,c4.w, d.x,d.y,d.z,d.w };
        #pragma unroll
        for (int q = 0; q < 16; ++q) {
            acc[2 * q + 0] += __uint_as_float(w[q] << 16);
            acc[2 * q + 1] += __uint_as_float(w[q] & 0xFFFF0000u);
        }
    }
    #pragma unroll
    for (int c = 0; c < C; ++c) {
        acc[c] += __shfl_xor(acc[c], 1);
        acc[c] += __shfl_xor(acc[c], 2);
        acc[c] += __shfl_xor(acc[c], 4);
    }
    ax += __shfl_xor(ax, 1); ax += __shfl_xor(ax, 2); ax += __shfl_xor(ax, 4);
    ay += __shfl_xor(ay, 1); ay += __shfl_xor(ay, 2); ay += __shfl_xor(ay, 4);
    az += __shfl_xor(az, 1); az += __shfl_xor(az, 2); az += __shfl_xor(az, 4);
    if (sub == 0) {
        float inv = 1.0f / fmaxf((float)n, 1.0f);
        float4* o4 = (float4*)(out_x + (size_t)sp * C);
        #pragma unroll
        for (int q = 0; q < 8; ++q) {
            float4 f;
            f.x = acc[4 * q + 0] * inv; f.y = acc[4 * q + 1] * inv;
            f.z = acc[4 * q + 2] * inv; f.w = acc[4 * q + 3] * inv;
            o4[q] = f;
        }
        out_xyz[3 * sp + 0] = ax * inv;
        out_xyz[3 * sp + 1] = ay * inv;
        out_xyz[3 * sp + 2] = az * inv;
    }
}

extern "C" void kernel_launch(void* const* d_in, const int* in_sizes, int n_in,
                              void* d_out, int out_size, void* d_ws, size_t ws_size,
                              hipStream_t stream)
{
    const float* voxel_feats = (const float*)d_in[0];
    const float* xyz         = (const float*)d_in[1];
    const float* W1          = (const float*)d_in[2];
    const float* b1          = (const float*)d_in[3];
    const float* gamma       = (const float*)d_in[4];
    const float* beta        = (const float*)d_in[5];
    const float* W2          = (const float*)d_in[6];
    const float* b2          = (const float*)d_in[7];
    const int*   p2v         = (const int*)d_in[8];
    const int*   sp_ids      = (const int*)d_in[9];

    const int n_pts = in_sizes[8];
    const int S     = out_size / 35;

    float* out_x   = (float*)d_out;
    float* out_xyz = out_x + (size_t)S * C;

    // head (ints): count[S] | off[S] | bsum[64] | rank[N]
    int* count = (int*)d_ws;
    int* off   = count + S;
    int* bsum  = off + S;
    int* rank  = bsum + 64;

    size_t head_b = ((size_t)2 * S + 64 + (size_t)n_pts) * sizeof(int);
    head_b = (head_b + 255) & ~(size_t)255;
    size_t xyzp_b = (size_t)n_pts * 16;
    size_t y_b    = (size_t)n_pts * 64;

    int blk = 256;
    int gpts = (n_pts + blk - 1) / blk;
    int nb = (S + SCAN_BLK - 1) / SCAN_BLK;
    int n_thr = S * P;

    hipMemsetAsync(count, 0, (size_t)S * sizeof(int), stream);

    if (ws_size >= head_b + xyzp_b + y_b) {
        uint4* xyzp = (uint4*)((char*)d_ws + head_b);
        uint4* y_s  = (uint4*)((char*)d_ws + head_b + xyzp_b);

        kA1_rank_mlp<<<gpts, blk, 0, stream>>>(
            voxel_feats, xyz, W1, b1, gamma, beta, W2, b2,
            p2v, sp_ids, count, rank, y_s, n_pts);
        k2a_scan_block<<<nb, SCAN_BLK, 0, stream>>>(count, off, bsum, S);
        k2b_scan_bsums<<<1, 64, 0, stream>>>(bsum, nb);
        k2c_add_prefix<<<(S + blk - 1) / blk, blk, 0, stream>>>(off, bsum, S);
        k3x_scatter16<<<gpts, blk, 0, stream>>>(sp_ids, rank, off, xyz, xyzp, n_pts);
        kB2_reduce<<<(n_thr + blk - 1) / blk, blk, 0, stream>>>(
            y_s, xyzp, off, count, out_x, out_xyz, S);
    } else {
        // R5 layout: head | order[N] | y_s
        int* order = rank + n_pts;
        size_t head5_b = ((size_t)2 * S + 64 + (size_t)2 * n_pts) * sizeof(int);
        head5_b = (head5_b + 255) & ~(size_t)255;
        uint4* y_s = (uint4*)((char*)d_ws + head5_b);

        kA1_rank_mlp<<<gpts, blk, 0, stream>>>(
            voxel_feats, xyz, W1, b1, gamma, beta, W2, b2,
            p2v, sp_ids, count, rank, y_s, n_pts);
        k2a_scan_block<<<nb, SCAN_BLK, 0, stream>>>(count, off, bsum, S);
        k2b_scan_bsums<<<1, 64, 0, stream>>>(bsum, nb);
        k2c_add_prefix<<<(S + blk - 1) / blk, blk, 0, stream>>>(off, bsum, S);
        k3_reorder<<<gpts, blk, 0, stream>>>(sp_ids, rank, off, order, n_pts);
        kB_gather_reduce<<<(n_thr + blk - 1) / blk, blk, 0, stream>>>(
            y_s, xyz, order, off, count, out_x, out_xyz, S);
    }
}